// Round 9
// baseline (1152.978 us; speedup 1.0000x reference)
//
#include <hip/hip_runtime.h>
#include <hip/hip_bf16.h>

// ---------------------------------------------------------------------------
// Bidirectional GRU encoder (Keras reset_after=true), B=64 S=512 U=256 V=32000
// Round 9: 256 thr/wg, 1 unit/thread, FULL k=256 per thread.
//   - no k-split => no shuffle reduction, h write = 1 ds_write_b16/thread
//   - __launch_bounds__(256,1): 4 waves/CU, 1/SIMD; VGPR budget 512/lane
//     (256 arch v + AGPR overflow; CDNA4 VALU reads AGPRs directly)
//   - U = 96 uint4 per thread (384 regs), loaded via coalesced blob layout
//   - 12 independent fdot2 accumulators (no dependent-chain stalls)
//   - h fp16 in LDS, double-buffered, broadcast b128 reads, 1 barrier/step
//   k0a wt_prep : W fp32 -> Wtb [dir][768][256] bf16 (transposed)
//   k0b u_prep  : U fp32 -> Upk [dir][q=96][t=256] uint4 (fp16-pair quads)
//   k1  gx_mfma : gx = emb[x] @ W + b_in (+ b_rec for z,r), bf16 MFMA
//   k2  gru     : 128 wgs = (dir,batch) = 1 chain/CU
// ws: [0,100663296) gx ; +786432 Wtb ; +786432 Upk   (~102.2 MB)
// ---------------------------------------------------------------------------

typedef _Float16 half2v __attribute__((ext_vector_type(2)));
typedef short short8 __attribute__((ext_vector_type(8)));
typedef float f32x4 __attribute__((ext_vector_type(4)));

__device__ __forceinline__ unsigned short f2bf(float f) {
  unsigned int u = __float_as_uint(f);
  return (unsigned short)((u + 0x7fffu + ((u >> 16) & 1u)) >> 16);  // RNE
}
__device__ __forceinline__ float bf2f(unsigned short v) {
  return __uint_as_float((unsigned int)v << 16);
}
__device__ __forceinline__ unsigned int packf16(float a, float b) {
  half2v v = {(_Float16)a, (_Float16)b};
  return __builtin_bit_cast(unsigned int, v);
}
__device__ __forceinline__ float dot2(unsigned int u, unsigned int hv, float acc) {
#if __has_builtin(__builtin_amdgcn_fdot2)
  return __builtin_amdgcn_fdot2(__builtin_bit_cast(half2v, u),
                                __builtin_bit_cast(half2v, hv), acc, false);
#else
  half2v a = __builtin_bit_cast(half2v, u), b = __builtin_bit_cast(half2v, hv);
  return acc + (float)a.x * (float)b.x + (float)a.y * (float)b.y;
#endif
}
__device__ __forceinline__ float sigf(float x) {
  return __builtin_amdgcn_rcpf(1.f + __expf(-x));
}
__device__ __forceinline__ float tanhfast(float x) {
  return 1.f - 2.f * __builtin_amdgcn_rcpf(1.f + __expf(2.f * x));
}

// ---------------- k0a: Wtb[dir][c][k] = bf16(W[k][c]) -----------------------
__global__ void __launch_bounds__(256) wt_prep_kernel(const float* __restrict__ Wf,
                                                      const float* __restrict__ Wb,
                                                      unsigned short* __restrict__ Wtb) {
  int o = blockIdx.x * 256 + threadIdx.x;
  if (o >= 2 * 768 * 256) return;
  int dir = o / (768 * 256);
  int rem = o % (768 * 256);
  int c = rem / 256, k = rem % 256;
  const float* W = dir ? Wb : Wf;
  Wtb[o] = f2bf(W[(size_t)k * 768 + c]);
}

// ---------------- k0b: U -> per-thread quad blobs, lane-interleaved ---------
// Upk[(dir*96 + q)*256 + t] = uint4; q = g*32 + c (g gate, c quad-of-pairs);
// element e (0..3): pair p = c*4+e, k = 2p: pack(U[k][g*256+t], U[k+1][g*256+t])
__global__ void __launch_bounds__(256) u_prep_kernel(const float* __restrict__ Uf,
                                                     const float* __restrict__ Ub,
                                                     uint4* __restrict__ Upk) {
  int id = blockIdx.x * 256 + threadIdx.x;   // 0 .. 2*96*256-1
  if (id >= 2 * 96 * 256) return;
  int t = id & 255;
  int q = (id >> 8) % 96;
  int dir = id / (96 * 256);
  int g = q >> 5, c = q & 31;
  const float* U = dir ? Ub : Uf;
  int col = g * 256 + t;
  unsigned int r[4];
#pragma unroll
  for (int e = 0; e < 4; ++e) {
    int k = (c * 4 + e) * 2;
    r[e] = packf16(U[(size_t)k * 768 + col], U[(size_t)(k + 1) * 768 + col]);
  }
  Upk[id] = (uint4){r[0], r[1], r[2], r[3]};
}

// ---------------- k1: gx = emb[x] @ W + bias, bf16 MFMA ---------------------
__global__ void __launch_bounds__(256) gx_mfma_kernel(
    const int* __restrict__ x, const float* __restrict__ emb,
    const unsigned short* __restrict__ Wtb,
    const float* __restrict__ bfv, const float* __restrict__ bbv,
    unsigned short* __restrict__ gx) {
  __shared__ __align__(16) unsigned short As[128 * 32];
  __shared__ __align__(16) unsigned short Bs[128 * 32];
  __shared__ int xid[128];

  int tid = threadIdx.x;
  int r0 = blockIdx.x * 128;
  int yt = blockIdx.y;
  int dir = (yt >= 6) ? 1 : 0;
  int c0 = (yt - dir * 6) * 128;
  const float* bv = dir ? bbv : bfv;
  const unsigned short* WtD = Wtb + (size_t)dir * 768 * 256;

  if (tid < 128) xid[tid] = x[r0 + tid];
  __syncthreads();

  int lane = tid & 63, w = tid >> 6;
  int wr = w >> 1, wc = w & 1;

  f32x4 acc[4][4] = {};

  for (int ks = 0; ks < 8; ++ks) {
#pragma unroll
    for (int i = 0; i < 2; ++i) {
      int s = tid + i * 256;
      int row = s >> 2, kslot = s & 3;
      int sw = kslot ^ ((row >> 2) & 3);
      const float* src = emb + (size_t)xid[row] * 256 + ks * 32 + kslot * 8;
      float4 f0 = *(const float4*)src;
      float4 f1 = *(const float4*)(src + 4);
      uint4 pa;
      pa.x = f2bf(f0.x) | ((unsigned)f2bf(f0.y) << 16);
      pa.y = f2bf(f0.z) | ((unsigned)f2bf(f0.w) << 16);
      pa.z = f2bf(f1.x) | ((unsigned)f2bf(f1.y) << 16);
      pa.w = f2bf(f1.z) | ((unsigned)f2bf(f1.w) << 16);
      *(uint4*)&As[row * 32 + sw * 8] = pa;
      uint4 pb = *(const uint4*)(WtD + (size_t)(c0 + row) * 256 + ks * 32 + kslot * 8);
      *(uint4*)&Bs[row * 32 + sw * 8] = pb;
    }
    __syncthreads();

    short8 a[4], b[4];
#pragma unroll
    for (int f = 0; f < 4; ++f) {
      int rowA = wr * 64 + f * 16 + (lane & 15);
      int swA = (lane >> 4) ^ ((rowA >> 2) & 3);
      a[f] = __builtin_bit_cast(short8, *(const uint4*)&As[rowA * 32 + swA * 8]);
      int rowB = wc * 64 + f * 16 + (lane & 15);
      int swB = (lane >> 4) ^ ((rowB >> 2) & 3);
      b[f] = __builtin_bit_cast(short8, *(const uint4*)&Bs[rowB * 32 + swB * 8]);
    }
#pragma unroll
    for (int fm = 0; fm < 4; ++fm)
#pragma unroll
      for (int fn = 0; fn < 4; ++fn)
        acc[fm][fn] = __builtin_amdgcn_mfma_f32_16x16x32_bf16(a[fm], b[fn], acc[fm][fn], 0, 0, 0);
    __syncthreads();
  }

#pragma unroll
  for (int fn = 0; fn < 4; ++fn) {
    int col = c0 + wc * 64 + fn * 16 + (lane & 15);
    float bias = bv[col] + (col < 512 ? bv[768 + col] : 0.f);
#pragma unroll
    for (int fm = 0; fm < 4; ++fm) {
      int rowb = r0 + wr * 64 + fm * 16 + (lane >> 4) * 4;
#pragma unroll
      for (int q = 0; q < 4; ++q) {
        gx[((size_t)dir * 32768 + rowb + q) * 768 + col] = f2bf(acc[fm][fn][q] + bias);
      }
    }
  }
}

// ---------------- k2: recurrence, 256 thr, full-k per thread ----------------
__global__ void __launch_bounds__(256, 1) gru_kernel(
    const uint4* __restrict__ Upk,           // [dir][96][256] fp16-pair quads
    const unsigned short* __restrict__ gx,   // [2][32768][768] bf16
    const int* __restrict__ x,
    const float* __restrict__ bfv, const float* __restrict__ bbv,
    float* __restrict__ out) {
  int wg = blockIdx.x;
  int dir = wg >> 6, b = wg & 63;
  int t = threadIdx.x;                        // unit j = t

  // h as fp16, 256 entries + pad; double-buffered. Reads are wave-broadcast
  // uint4s (same addr across lanes -> free); writes are per-thread b16.
  __shared__ __align__(16) _Float16 h_lds[2][264];

  const float brh = (dir ? bbv : bfv)[1280 + t];
  const unsigned short* gxd = gx + ((size_t)dir * 32768 + (size_t)b * 512) * 768;
  const int* xb = x + b * 512;
  float* outb = out + ((size_t)b << 17);

  // one-time: 96 coalesced uint4 loads (lane-interleaved layout)
  uint4 uz4[32], ur4[32], uh4[32];
  {
    const uint4* ub = Upk + (size_t)dir * 96 * 256 + t;
#pragma unroll
    for (int c = 0; c < 32; ++c) uz4[c] = ub[(0 * 32 + c) * 256];
#pragma unroll
    for (int c = 0; c < 32; ++c) ur4[c] = ub[(1 * 32 + c) * 256];
#pragma unroll
    for (int c = 0; c < 32; ++c) uh4[c] = ub[(2 * 32 + c) * 256];
  }
  {
    unsigned int* hz = (unsigned int*)h_lds;   // 264 uints total (2*264*2B)
    hz[t] = 0u;
    if (t < 264 - 256) hz[256 + t] = 0u;
  }
  __syncthreads();

  // prologue: preload step 0's gx + mask
  int tt0 = dir ? 511 : 0;
  const unsigned short* g0 = gxd + (size_t)tt0 * 768;
  float gz = bf2f(g0[t]), gr = bf2f(g0[256 + t]), gh = bf2f(g0[512 + t]);
  int xv = xb[tt0];

  float hj = 0.f;
  int cur = 0;
  for (int step = 0; step < 512; ++step) {
    int tcur = dir ? (511 - step) : step;
    // prefetch next step (latency hidden under dot loop)
    float gz_n = 0.f, gr_n = 0.f, gh_n = 0.f;
    int xv_n = 0;
    if (step < 511) {
      int tn = dir ? (510 - step) : (step + 1);
      const unsigned short* gn = gxd + (size_t)tn * 768;
      gz_n = bf2f(gn[t]); gr_n = bf2f(gn[256 + t]); gh_n = bf2f(gn[512 + t]);
      xv_n = xb[tn];
    }

    // 12 independent accumulators: no dependent fdot2 chains
    float az0 = 0.f, az1 = 0.f, az2 = 0.f, az3 = 0.f;
    float ar0 = 0.f, ar1 = 0.f, ar2 = 0.f, ar3 = 0.f;
    float ah0 = 0.f, ah1 = 0.f, ah2 = 0.f, ah3 = 0.f;
    const uint4* h4 = (const uint4*)&h_lds[cur][0];
#pragma unroll
    for (int c = 0; c < 32; ++c) {
      uint4 hv = h4[c];                        // broadcast, conflict-free
      uint4 a = uz4[c], r = ur4[c], d = uh4[c];
      az0 = dot2(a.x, hv.x, az0);
      az1 = dot2(a.y, hv.y, az1);
      az2 = dot2(a.z, hv.z, az2);
      az3 = dot2(a.w, hv.w, az3);
      ar0 = dot2(r.x, hv.x, ar0);
      ar1 = dot2(r.y, hv.y, ar1);
      ar2 = dot2(r.z, hv.z, ar2);
      ar3 = dot2(r.w, hv.w, ar3);
      ah0 = dot2(d.x, hv.x, ah0);
      ah1 = dot2(d.y, hv.y, ah1);
      ah2 = dot2(d.z, hv.z, ah2);
      ah3 = dot2(d.w, hv.w, ah3);
    }
    float az = (az0 + az1) + (az2 + az3);
    float ar = (ar0 + ar1) + (ar2 + ar3);
    float ah = (ah0 + ah1) + (ah2 + ah3);

    float z = sigf(gz + az);
    float r = sigf(gr + ar);
    float hh = tanhfast(gh + r * (ah + brh));
    float hn = hh + z * (hj - hh);
    hn = (xv == 0) ? hj : hn;                  // masked: carry state

    h_lds[cur ^ 1][t] = (_Float16)hn;          // per-thread b16 write
    __syncthreads();                           // single barrier per step

    atomicAdd(&outb[(size_t)tcur * 256 + t], hn);
    hj = hn; gz = gz_n; gr = gr_n; gh = gh_n; xv = xv_n;
    cur ^= 1;
  }
}

// ---------------------------------------------------------------------------
extern "C" void kernel_launch(void* const* d_in, const int* in_sizes, int n_in,
                              void* d_out, int out_size, void* d_ws, size_t ws_size,
                              hipStream_t stream) {
  const int*   x   = (const int*)d_in[0];
  const float* emb = (const float*)d_in[1];
  const float* Wf  = (const float*)d_in[2];
  const float* Uf  = (const float*)d_in[3];
  const float* bf_ = (const float*)d_in[4];
  const float* Wb  = (const float*)d_in[5];
  const float* Ub  = (const float*)d_in[6];
  const float* bb_ = (const float*)d_in[7];
  float* out = (float*)d_out;

  unsigned short* gxp = (unsigned short*)d_ws;                        // 100663296 B
  unsigned short* Wtb = (unsigned short*)((char*)d_ws + 100663296);   // 786432 B
  uint4*          Upk = (uint4*)((char*)d_ws + 100663296 + 786432);   // 786432 B

  hipMemsetAsync(d_out, 0, (size_t)out_size * sizeof(float), stream);

  wt_prep_kernel<<<1536, 256, 0, stream>>>(Wf, Wb, Wtb);
  u_prep_kernel<<<192, 256, 0, stream>>>(Uf, Ub, Upk);
  gx_mfma_kernel<<<dim3(256, 12), 256, 0, stream>>>(x, emb, Wtb, bf_, bb_, gxp);
  gru_kernel<<<128, 256, 0, stream>>>(Upk, gxp, x, bf_, bb_, out);
}